// Round 8
// baseline (86.367 us; speedup 1.0000x reference)
//
#include <hip/hip_runtime.h>
#include <math.h>

#define DIM 256
typedef float v2f  __attribute__((ext_vector_type(2)));
typedef _Float16 f16x8 __attribute__((ext_vector_type(8)));
typedef _Float16 f16x4 __attribute__((ext_vector_type(4)));
typedef float f32x4 __attribute__((ext_vector_type(4)));

__device__ __forceinline__ v2f mk2(float a, float b) { v2f r; r.x = a; r.y = b; return r; }
__device__ __forceinline__ float rl(float v, int l) {
    return __uint_as_float(__builtin_amdgcn_readlane(__float_as_uint(v), l));
}

template<int B2>
__device__ __forceinline__ void ry_pk(v2f* v, float c, float s) {
#pragma unroll
    for (int p = 0; p < 16; ++p)
        if (!(p & (1 << B2))) {
            const int q = p | (1 << B2);
            v2f lo = v[p], hi = v[q];
            v[p] = c * lo - s * hi;
            v[q] = s * lo + c * hi;
        }
}
__device__ __forceinline__ void ry_intra(v2f* v, float c, float s) {
#pragma unroll
    for (int p = 0; p < 16; ++p) {
        float lo = v[p].x, hi = v[p].y;
        v[p].x = fmaf(-s, hi, c * lo);
        v[p].y = fmaf(s, lo, c * hi);
    }
}

// ---------------------------------------------------------------------------
// Stage 1 (unchanged from R7, verified): build U (256x256 real orthogonal),
// store fp16 MFMA A-frags mt-major with coalesced 16 B stores:
//   uf[((mt*8 + ks)*64 + lf)*8 + j] = U[m][k], m = 16mt+(lf&15), k = 32ks+(lf>>4)*8+j.
// Dropped exactly (commute with observables on wires 6,7): w18..21, w24, w25.
// ---------------------------------------------------------------------------
__global__ __launch_bounds__(256) void qae_buildU(const float* __restrict__ w,
                                                  _Float16* __restrict__ uf) {
    __shared__ float4 lds4[2048];
    const int lane = threadIdx.x & 63;
    const int wid  = threadIdx.x >> 6;
    const int wave = blockIdx.x * 4 + wid;
    const int l3   = lane & 7;
    const int e    = lane >> 3;
    const int col  = wave * 8 + e;
    float4* W = lds4 + wid * 512 + e * 64;

    float h = 0.f;
    if (lane < 20) h = 0.5f * w[lane < 18 ? lane : lane + 4];
    const float cv = __cosf(h), sv = __sinf(h);
#define RYP(B2, slot) ry_pk<B2>(v, rl(cv, slot), rl(sv, slot))
#define RYI(slot)     ry_intra(v, rl(cv, slot), rl(sv, slot))

    const int a0 = (l3 >> 2) & 1, a1 = (l3 >> 1) & 1, a2 = l3 & 1;
    const int aa = a0 & a1, dd = a0 ^ a1;
    const float fE = (aa ^ (dd & a2)) ? -1.f : 1.f;
    const float fO = ((aa ^ (dd & a2)) ^ dd) ? -1.f : 1.f;
    const float pB = (__popc(l3) & 1) ? -1.f : 1.f;
    const v2f mA0 = mk2(fE, fO), mA1 = mk2(fO, fE);
    const v2f mBp = mk2(pB, -pB);

    v2f v[16];
#pragma unroll
    for (int p = 0; p < 16; ++p) v[p] = mk2(0.f, 0.f);
    if (((col >> 2) & 7) == l3) {
        const int p = 2 * (col >> 5) + ((col >> 1) & 1);
        if (col & 1) v[p].y = 1.f; else v[p].x = 1.f;
    }

    RYP(3, 0); RYP(2, 1); RYP(1, 2);
#pragma unroll
    for (int g = 0; g < 8; ++g)
        W[g * 8 + (l3 ^ g)] = make_float4(v[2*g].x, v[2*g].y, v[2*g+1].x, v[2*g+1].y);
#pragma unroll
    for (int k = 0; k < 8; ++k) {
        float4 f = W[l3 * 8 + (k ^ l3)];
        v[2*k] = mk2(f.x, f.y); v[2*k+1] = mk2(f.z, f.w);
    }
    RYP(3, 3); RYP(2, 4); RYP(1, 5); RYP(0, 6); RYI(7);
#pragma unroll
    for (int p = 0; p < 16; ++p) v[p] *= (__popc(p) & 1) ? mA1 : mA0;
    RYP(3, 11); RYP(2, 12); RYP(1, 13); RYP(0, 14); RYI(15);
#pragma unroll
    for (int k = 0; k < 8; ++k)
        W[l3 * 8 + (k ^ l3)] = make_float4(v[2*k].x, v[2*k].y, v[2*k+1].x, v[2*k+1].y);
#pragma unroll
    for (int g = 0; g < 8; ++g) {
        float4 f = W[g * 8 + (l3 ^ g)];
        v[2*g] = mk2(f.x, f.y); v[2*g+1] = mk2(f.z, f.w);
    }
    RYP(3, 8); RYP(2, 9); RYP(1, 10);
#pragma unroll
    for (int p = 0; p < 16; ++p) {
        const int b0 = (p >> 3) & 1, b1 = (p >> 2) & 1;
        if (b0 & b1)      v[p] = -v[p];
        else if (b0 ^ b1) v[p] *= (__popc(p & 3) & 1) ? -mBp : mBp;
    }
    RYP(3, 16); RYP(2, 17); RYP(0, 18); RYI(19);
#pragma unroll
    for (int p = 0; p < 16; ++p) {
        const int b0 = (p >> 3) & 1, b1 = (p >> 2) & 1;
        if (b0 & b1)      v[p] = -v[p];
        else if (b0 ^ b1) v[p] *= (__popc(p & 3) & 1) ? -mBp : mBp;
    }
#undef RYP
#undef RYI

    _Float16* T = (_Float16*)(lds4 + wid * 512);
#pragma unroll
    for (int p = 0; p < 16; ++p) {
        const int m0 = ((p >> 1) << 5) | (l3 << 2) | ((p & 1) << 1);
        T[m0 * 8 + e]       = (_Float16)v[p].x;
        T[(m0 + 1) * 8 + e] = (_Float16)v[p].y;
    }
    const int ksv = wave >> 2, lfh = (wave & 3) << 4;
#pragma unroll
    for (int i = 0; i < 4; ++i) {
        const int m = lane * 4 + i;
        const int mt = m >> 4, lf = (m & 15) | lfh;
        f16x8 t = *(const f16x8*)(T + m * 8);
        *(f16x8*)(uf + (size_t)(((mt * 8 + ksv) * 64 + lf) * 8)) = t;
    }
}

// ---------------------------------------------------------------------------
// Stage 2: U held in REGISTERS, m-split across the 4 waves (wave w owns
// m in [64w,64w+64): af[4][8] = 128 VGPRs, loaded once per block). Per beat:
// stage 16 x-rows -> LDS (stride 264 f16: bf reads at free 2-way floor),
// 32 MFMAs, in-lane observables, cross-wave LDS reduce. Xs/Nb double-buffered.
// C layout: col=lane&15=batch, row=(lane>>4)*4+reg -> (w6,w7) quad in-lane.
// ---------------------------------------------------------------------------
__global__ __launch_bounds__(256, 2) void qae_gemm(const float* __restrict__ x,
                                                   const _Float16* __restrict__ uf,
                                                   float* __restrict__ out,
                                                   int batch, int strips) {
    __shared__ __align__(16) _Float16 Xs[2][16 * 264];  // 2 x 8448 B
    __shared__ __align__(16) float Nb[2][16][20];       // norm partials (padded)
    __shared__ __align__(16) float Ps[4][16][8];        // 7 obs partials per wave
    const int tid  = threadIdx.x;
    const int lane = tid & 63, wid = tid >> 6;
    const int bl   = lane & 15, bq = lane >> 4;
    const int r    = tid >> 4,  q  = tid & 15;          // staging assignment

    // U quarter into registers (coalesced b128, once per block)
    f16x8 af[4][8];
#pragma unroll
    for (int mtl = 0; mtl < 4; ++mtl)
#pragma unroll
        for (int ks = 0; ks < 8; ++ks)
            af[mtl][ks] = *(const f16x8*)(uf +
                (size_t)((((wid * 4 + mtl) * 8 + ks) * 64 + lane) * 8));

    int p = 0;
    for (int strip = blockIdx.x; strip < strips; strip += gridDim.x) {
        __syncthreads();                                // prev beat's Ps/Nb consumed
        // ---- stage 16 rows (fp32->fp16) + fp32 norm partials ----
        int gr = strip * 16 + r; if (gr >= batch) gr = batch - 1;
        const float* xr = x + (size_t)gr * DIM;
        float ns = 0.f;
#pragma unroll
        for (int i = 0; i < 4; ++i) {
            const int c = q + i * 16;                   // float4 chunk 0..63
            const float4 f = *(const float4*)(xr + c * 4);
            ns += f.x*f.x + f.y*f.y + f.z*f.z + f.w*f.w;
            f16x4 hh;
            hh[0] = (_Float16)f.x; hh[1] = (_Float16)f.y;
            hh[2] = (_Float16)f.z; hh[3] = (_Float16)f.w;
            *(f16x4*)(Xs[p] + r * 264 + c * 4) = hh;
        }
        Nb[p][r][q] = ns;
        __syncthreads();                                // Xs[p]/Nb[p] ready

        // ---- B-frags (2-way bank floor thanks to 264 stride) ----
        f16x8 bf[8];
#pragma unroll
        for (int ks = 0; ks < 8; ++ks)
            bf[ks] = *(const f16x8*)(Xs[p] + bl * 264 + ks * 32 + bq * 8);

        // ---- 32 MFMAs + in-lane observables ----
        float pX6 = 0, pX7 = 0, pXX = 0, pYY = 0, pZ6 = 0, pZ7 = 0, pZZ = 0;
#pragma unroll
        for (int mtl = 0; mtl < 4; ++mtl) {
            f32x4 acc = {0.f, 0.f, 0.f, 0.f};
#pragma unroll
            for (int ks = 0; ks < 8; ++ks)
                acc = __builtin_amdgcn_mfma_f32_16x16x32_f16(af[mtl][ks], bf[ks],
                                                             acc, 0, 0, 0);
            const float q0 = acc[0], q1 = acc[1], q2 = acc[2], q3 = acc[3];
            pX6 += q0*q2 + q1*q3;  pX7 += q0*q1 + q2*q3;
            pXX += q0*q3 + q1*q2;  pYY += q1*q2 - q0*q3;
            const float s0 = q0*q0, s1 = q1*q1, s2 = q2*q2, s3 = q3*q3;
            pZ6 += (s0 + s1) - (s2 + s3);
            pZ7 += (s0 - s1) + (s2 - s3);
            pZZ += (s0 - s1) - (s2 - s3);
        }
#pragma unroll
        for (int m = 16; m <= 32; m <<= 1) {
            pX6 += __shfl_xor(pX6, m); pX7 += __shfl_xor(pX7, m);
            pXX += __shfl_xor(pXX, m); pYY += __shfl_xor(pYY, m);
            pZ6 += __shfl_xor(pZ6, m); pZ7 += __shfl_xor(pZ7, m);
            pZZ += __shfl_xor(pZZ, m);
        }
        if (bq == 0) {
            float* ps = Ps[wid][bl];
            ps[0] = pX6; ps[1] = pX7; ps[2] = pXX; ps[3] = pYY;
            ps[4] = pZ6; ps[5] = pZ7; ps[6] = pZZ;
        }
        __syncthreads();                                // Ps ready

        // ---- cross-wave reduce + store: lane = col*4 + w ----
        {
            const int col = lane >> 2, wq = lane & 3;
            const float4 pa = *(const float4*)&Ps[wq][col][0];
            const float4 pb = *(const float4*)&Ps[wq][col][4];
            const float4 nn = *(const float4*)&Nb[p][col][wq * 4];
            float aX6 = pa.x, aX7 = pa.y, aXX = pa.z, aYY = pa.w;
            float aZ6 = pb.x, aZ7 = pb.y, aZZ = pb.z;
            float an  = nn.x + nn.y + nn.z + nn.w;
#pragma unroll
            for (int m = 1; m <= 2; m <<= 1) {
                aX6 += __shfl_xor(aX6, m); aX7 += __shfl_xor(aX7, m);
                aXX += __shfl_xor(aXX, m); aYY += __shfl_xor(aYY, m);
                aZ6 += __shfl_xor(aZ6, m); aZ7 += __shfl_xor(aZ7, m);
                aZZ += __shfl_xor(aZZ, m); an  += __shfl_xor(an, m);
            }
            const int ob = strip * 16 + col;
            if (wq == 0 && ob < batch) {
                const float inv = 1.f / an;             // U orthogonal
                float* o = out + (size_t)ob * 9;
                o[0] = 2.f * aX6 * inv;  o[1] = 0.f;  o[2] = aZ6 * inv;
                o[3] = 2.f * aX7 * inv;  o[4] = 0.f;  o[5] = aZ7 * inv;
                o[6] = 2.f * aXX * inv;  o[7] = 2.f * aYY * inv;  o[8] = aZZ * inv;
            }
        }
        p ^= 1;
    }
}

extern "C" void kernel_launch(void* const* d_in, const int* in_sizes, int n_in,
                              void* d_out, int out_size, void* d_ws, size_t ws_size,
                              hipStream_t stream) {
    const float* x = (const float*)d_in[0];
    const float* w = (const float*)d_in[1];
    float* out = (float*)d_out;
    _Float16* uf = (_Float16*)d_ws;                     // 128 KB of fragments
    const int batch = in_sizes[0] / DIM;

    qae_buildU<<<8, 256, 0, stream>>>(w, uf);

    const int strips = (batch + 15) / 16;
    int blocks = 512; if (blocks > strips) blocks = strips;
    qae_gemm<<<blocks, 256, 0, stream>>>(x, uf, out, batch, strips);
}